// Round 1
// baseline (978.102 us; speedup 1.0000x reference)
//
#include <hip/hip_runtime.h>

// Problem geometry (fixed by reference)
#define WINS 7
#define H 160
#define W 160
#define DD 96
#define HO 154          // H - WINS + 1
#define WO 154
#define DOUT 90
#define CSTRIDE (H*W*DD)   // per-(b,c) channel stride = 2,457,600

// Tile config
#define TH 8
#define TW 8
#define TD 16
#define IH (TH + WINS - 1)   // 14
#define IW (TW + WINS - 1)   // 14
#define HTILES ((HO + TH - 1) / TH)   // 20
#define WTILES ((WO + TW - 1) / TW)   // 20
#define DTILES ((DOUT + TD - 1) / TD) // 6
#define NBC 8                          // B*C = 2*4 channels

#define COL_STRIDE 17   // LDS column stride (16 d-outputs + 1 pad -> no 32-way bank conflict)

__device__ __forceinline__ void field_at(const float* __restrict__ xp,
                                         const int* __restrict__ yp,
                                         int d, int cl,
                                         float& f0, float& f1, float& f2) {
    d = min(d, DD - 1);            // clamp; clamped lanes never feed valid outputs
    float xv = xp[d];
    int   yv = yp[d];
    float m  = (yv == cl) ? 1.0f : 0.0f;
    float sg = 1.0f / (1.0f + __expf(-xv));
    f0 = m;
    f1 = m * sg;
    f2 = m * sg * sg;
}

__global__ __launch_bounds__(256)
void structure_loss_main(const float* __restrict__ x,
                         const int* __restrict__ y,
                         double* __restrict__ acc) {
    // LDS: stage-A (D-window sums) and stage-B (W-window sums), 3 fields each
    __shared__ float sA[3][IH * IW * COL_STRIDE];   // 3*196*17*4 = 39,984 B
    __shared__ float sB[3][IH * TW * COL_STRIDE];   // 3*112*17*4 = 22,848 B
    __shared__ float wsum[4];

    const int dt = blockIdx.x;                 // 0..5
    const int wt = blockIdx.y;                 // 0..19
    const int z  = blockIdx.z;                 // 0..159
    const int bc = z / HTILES;
    const int ht = z - bc * HTILES;
    const int b  = bc >> 2;
    const int cl = bc & 3;

    const int h0 = ht * TH, w0 = wt * TW, d0 = dt * TD;

    const float* xc = x + ((size_t)b * 4 + cl) * (size_t)CSTRIDE;
    const int*   yc = y + (size_t)b * (size_t)CSTRIDE;

    const int t = threadIdx.x;

    // ---- Stage A: sliding 7-window along D per (ih,iw) column ----
    if (t < IH * IW) {
        const int ih = t / IW, iw = t - ih * IW;
        const int h = min(h0 + ih, H - 1);
        const int w = min(w0 + iw, W - 1);
        const float* xp = xc + ((size_t)h * W + w) * DD;
        const int*   yp = yc + ((size_t)h * W + w) * DD;

        float s0 = 0.f, s1 = 0.f, s2 = 0.f, f0, f1, f2;
#pragma unroll
        for (int k = 0; k < WINS; k++) {
            field_at(xp, yp, d0 + k, cl, f0, f1, f2);
            s0 += f0; s1 += f1; s2 += f2;
        }
        const int base = t * COL_STRIDE;
        sA[0][base] = s0; sA[1][base] = s1; sA[2][base] = s2;
#pragma unroll
        for (int dn = 1; dn < TD; dn++) {
            field_at(xp, yp, d0 + dn + WINS - 1, cl, f0, f1, f2);
            s0 += f0; s1 += f1; s2 += f2;
            field_at(xp, yp, d0 + dn - 1, cl, f0, f1, f2);
            s0 -= f0; s1 -= f1; s2 -= f2;
            sA[0][base + dn] = s0; sA[1][base + dn] = s1; sA[2][base + dn] = s2;
        }
    }
    __syncthreads();

    // ---- Stage B: 7-window along W.  Items: (ih in 14, wo in 8, dn in 16) = 1792 ----
    for (int item = t; item < IH * TW * TD; item += 256) {
        const int dn = item & (TD - 1);
        const int wo = (item >> 4) & (TW - 1);
        const int ih = item >> 7;
        float b0 = 0.f, b1 = 0.f, b2 = 0.f;
#pragma unroll
        for (int j = 0; j < WINS; j++) {
            const int idx = (ih * IW + wo + j) * COL_STRIDE + dn;
            b0 += sA[0][idx]; b1 += sA[1][idx]; b2 += sA[2][idx];
        }
        const int o = (ih * TW + wo) * COL_STRIDE + dn;
        sB[0][o] = b0; sB[1][o] = b1; sB[2][o] = b2;
    }
    __syncthreads();

    // ---- Stage C: 7-window along H + s_value + block reduction ----
    float lsum = 0.f;
    for (int item = t; item < TH * TW * TD; item += 256) {
        const int dn = item & (TD - 1);
        const int wo = (item >> 4) & (TW - 1);
        const int ho = item >> 7;
        const int hg = h0 + ho, wg = w0 + wo, dg = d0 + dn;
        if (hg < HO && wg < WO && dg < DOUT) {
            float c0 = 0.f, c1 = 0.f, c2 = 0.f;
#pragma unroll
            for (int i = 0; i < WINS; i++) {
                const int idx = ((ho + i) * TW + wo) * COL_STRIDE + dn;
                c0 += sB[0][idx]; c1 += sB[1][idx]; c2 += sB[2][idx];
            }
            // c0=S_m, c1=S_tm, c2=S_t2m
            const float S_t  = c1 + 0.5f  * (343.0f - c0);
            const float S_t2 = c2 + 0.25f * (343.0f - c0);
            const float inv = 1.0f / 343.0f;
            const float ux  = S_t  * inv;
            const float uy  = c0   * inv;
            const float uxx = S_t2 * inv;
            const float uxy = c1   * inv;
            const float covn = 49.0f / 48.0f;   // WIN^2/(WIN^2-1), faithful to reference
            const float cc   = 0.00045f;        // (0.03 * data_range)^2 / 2, data_range==1
            const float vx  = covn * (uxx - ux * ux);
            const float vy  = covn * (uy  - uy * uy);
            const float vxy = covn * (uxy - ux * uy);
            lsum += (vxy + cc) / (vx * vy + cc);
        }
    }

    // wave(64) shuffle reduce, then cross-wave via LDS
#pragma unroll
    for (int off = 32; off > 0; off >>= 1) lsum += __shfl_down(lsum, off, 64);
    const int wave = t >> 6;
    if ((t & 63) == 0) wsum[wave] = lsum;
    __syncthreads();
    if (t == 0) {
        const float s = wsum[0] + wsum[1] + wsum[2] + wsum[3];
        atomicAdd(acc, (double)s);
    }
}

__global__ void structure_loss_finalize(const double* __restrict__ acc,
                                        float* __restrict__ out) {
    out[0] = 1.0f - (float)(acc[0] / 17075520.0);   // 8*154*154*90
}

extern "C" void kernel_launch(void* const* d_in, const int* in_sizes, int n_in,
                              void* d_out, int out_size, void* d_ws, size_t ws_size,
                              hipStream_t stream) {
    const float* x = (const float*)d_in[0];
    const int*   y = (const int*)d_in[1];
    double* acc = (double*)d_ws;

    hipMemsetAsync(d_ws, 0, sizeof(double), stream);

    dim3 grid(DTILES, WTILES, NBC * HTILES);   // (6, 20, 160) = 19200 blocks
    structure_loss_main<<<grid, 256, 0, stream>>>(x, y, acc);
    structure_loss_finalize<<<1, 1, 0, stream>>>(acc, (float*)d_out);
}

// Round 2
// 444.135 us; speedup vs baseline: 2.2023x; 2.2023x over previous
//
#include <hip/hip_runtime.h>

// Problem geometry (fixed by reference)
#define WINS 7
#define H 160
#define W 160
#define DD 96
#define HO 154          // H - WINS + 1
#define WO 154
#define DOUT 90
#define CSTRIDE (H*W*DD)   // per-(b,c) channel stride = 2,457,600

// Tile config
#define TH 8
#define TW 8
#define TD 16
#define IH (TH + WINS - 1)   // 14
#define IW (TW + WINS - 1)   // 14
#define NCOL (IH * IW)       // 196 columns
#define ID 24                // staged d-extent per column (22 needed, padded to 6xfloat4)
#define NV 6                 // float4s per column
#define HTILES ((HO + TH - 1) / TH)   // 20
#define WTILES ((WO + TW - 1) / TW)   // 20
#define DTILES ((DOUT + TD - 1) / TD) // 6
#define NBC 8                          // B*C = 2*4 channels

#define COL_STRIDE 17   // LDS column stride for sA/sB (16 + 1 pad)

__global__ __launch_bounds__(256)
void structure_loss_main(const float* __restrict__ x,
                         const int* __restrict__ y,
                         double* __restrict__ acc) {
    // sA: D-window sums of the 3 fields. 3*196*17*4 = 39,984 B
    __shared__ float sA[3][NCOL * COL_STRIDE];
    // vs (staging, phase 0/A) and sB (phase B/C) are never live together
    __shared__ union {
        float vs[NCOL * ID];            // 196*24*4 = 18,816 B
        float sB[3][IH * TW * COL_STRIDE]; // 3*112*17*4 = 22,848 B
    } u;
    __shared__ float wsum[4];

    const int dt = blockIdx.x;                 // 0..5
    const int wt = blockIdx.y;                 // 0..19
    const int z  = blockIdx.z;                 // 0..159
    const int bc = z / HTILES;
    const int ht = z - bc * HTILES;
    const int b  = bc >> 2;
    const int cl = bc & 3;

    const int h0 = ht * TH, w0 = wt * TW, d0 = dt * TD;

    const float* xc = x + ((size_t)b * 4 + cl) * (size_t)CSTRIDE;
    const int*   yc = y + (size_t)b * (size_t)CSTRIDE;

    const int t = threadIdx.x;

    // ---- Phase 0: coalesced vector staging. v = (y==cl ? +sigmoid(x) : -sigmoid(x)) ----
    // sign bit encodes the one-hot mask; magnitude is the sigmoid. One exp per element.
    for (int i = t; i < NCOL * NV; i += 256) {          // 1176 float4-items, ~5 iters
        const int col = i / NV, q = i - col * NV;
        const int ih = col / IW, iw = col - ih * IW;
        const int h = min(h0 + ih, H - 1);
        const int w = min(w0 + iw, W - 1);
        const int dbase = d0 + 4 * q;
        float4 vv;
        if (dbase < DD) {   // d0%16==0, so the float4 is entirely in [0,96)
            const size_t off = ((size_t)h * W + w) * DD + dbase;
            const float4 xv = *(const float4*)(xc + off);
            const int4   yv = *(const int4*)(yc + off);
            const float s0 = 1.0f / (1.0f + __expf(-xv.x));
            const float s1 = 1.0f / (1.0f + __expf(-xv.y));
            const float s2 = 1.0f / (1.0f + __expf(-xv.z));
            const float s3 = 1.0f / (1.0f + __expf(-xv.w));
            vv.x = (yv.x == cl) ? s0 : -s0;
            vv.y = (yv.y == cl) ? s1 : -s1;
            vv.z = (yv.z == cl) ? s2 : -s2;
            vv.w = (yv.w == cl) ? s3 : -s3;
        } else {
            vv = make_float4(0.f, 0.f, 0.f, 0.f);       // feeds only discarded outputs
        }
        *(float4*)&u.vs[col * ID + 4 * q] = vv;
    }
    __syncthreads();

    // ---- Phase A: 7-window along D. Items: (col in 196, dn in 16) = 3136 ----
    for (int item = t; item < NCOL * TD; item += 256) {
        const int dn = item & (TD - 1);
        const int col = item >> 4;
        float s0 = 0.f, s1 = 0.f, s2 = 0.f;
#pragma unroll
        for (int j = 0; j < WINS; j++) {
            const float v = u.vs[col * ID + dn + j];
            const float p = fmaxf(v, 0.f);
            s0 += (v > 0.f) ? 1.f : 0.f;   // m
            s1 += p;                        // m*sig
            s2 += p * v;                    // m*sig^2
        }
        const int o = col * COL_STRIDE + dn;
        sA[0][o] = s0; sA[1][o] = s1; sA[2][o] = s2;
    }
    __syncthreads();   // also retires all vs reads before sB overwrites the union

    // ---- Phase B: 7-window along W. Items: (ih in 14, wo in 8, dn in 16) = 1792 ----
    for (int item = t; item < IH * TW * TD; item += 256) {
        const int dn = item & (TD - 1);
        const int wo = (item >> 4) & (TW - 1);
        const int ih = item >> 7;
        float b0 = 0.f, b1 = 0.f, b2 = 0.f;
#pragma unroll
        for (int j = 0; j < WINS; j++) {
            const int idx = (ih * IW + wo + j) * COL_STRIDE + dn;
            b0 += sA[0][idx]; b1 += sA[1][idx]; b2 += sA[2][idx];
        }
        const int o = (ih * TW + wo) * COL_STRIDE + dn;
        u.sB[0][o] = b0; u.sB[1][o] = b1; u.sB[2][o] = b2;
    }
    __syncthreads();

    // ---- Phase C: 7-window along H + s_value + block reduction ----
    float lsum = 0.f;
    for (int item = t; item < TH * TW * TD; item += 256) {
        const int dn = item & (TD - 1);
        const int wo = (item >> 4) & (TW - 1);
        const int ho = item >> 7;
        const int hg = h0 + ho, wg = w0 + wo, dg = d0 + dn;
        if (hg < HO && wg < WO && dg < DOUT) {
            float c0 = 0.f, c1 = 0.f, c2 = 0.f;
#pragma unroll
            for (int i = 0; i < WINS; i++) {
                const int idx = ((ho + i) * TW + wo) * COL_STRIDE + dn;
                c0 += u.sB[0][idx]; c1 += u.sB[1][idx]; c2 += u.sB[2][idx];
            }
            // c0=S_m, c1=S_tm, c2=S_t2m ; t = m?sig:0.5 off-mask
            const float S_t  = c1 + 0.5f  * (343.0f - c0);
            const float S_t2 = c2 + 0.25f * (343.0f - c0);
            const float inv = 1.0f / 343.0f;
            const float ux  = S_t  * inv;
            const float uy  = c0   * inv;
            const float uxx = S_t2 * inv;
            const float uxy = c1   * inv;
            const float covn = 49.0f / 48.0f;   // WIN^2/(WIN^2-1)
            const float cc   = 0.00045f;        // (0.03*data_range)^2/2, data_range==1
            const float vx  = covn * (uxx - ux * ux);
            const float vy  = covn * (uy  - uy * uy);
            const float vxy = covn * (uxy - ux * uy);
            lsum += (vxy + cc) / (vx * vy + cc);
        }
    }

    // wave(64) shuffle reduce, then cross-wave via LDS
#pragma unroll
    for (int off = 32; off > 0; off >>= 1) lsum += __shfl_down(lsum, off, 64);
    const int wave = t >> 6;
    if ((t & 63) == 0) wsum[wave] = lsum;
    __syncthreads();
    if (t == 0) {
        const float s = wsum[0] + wsum[1] + wsum[2] + wsum[3];
        atomicAdd(acc, (double)s);
    }
}

__global__ void structure_loss_finalize(const double* __restrict__ acc,
                                        float* __restrict__ out) {
    out[0] = 1.0f - (float)(acc[0] / 17075520.0);   // 8*154*154*90
}

extern "C" void kernel_launch(void* const* d_in, const int* in_sizes, int n_in,
                              void* d_out, int out_size, void* d_ws, size_t ws_size,
                              hipStream_t stream) {
    const float* x = (const float*)d_in[0];
    const int*   y = (const int*)d_in[1];
    double* acc = (double*)d_ws;

    hipMemsetAsync(d_ws, 0, sizeof(double), stream);

    dim3 grid(DTILES, WTILES, NBC * HTILES);   // (6, 20, 160) = 19200 blocks
    structure_loss_main<<<grid, 256, 0, stream>>>(x, y, acc);
    structure_loss_finalize<<<1, 1, 0, stream>>>(acc, (float*)d_out);
}

// Round 3
// 371.463 us; speedup vs baseline: 2.6331x; 1.1956x over previous
//
#include <hip/hip_runtime.h>

// Problem geometry (fixed by reference)
#define WINS 7
#define H 160
#define W 160
#define DD 96
#define HO 154          // H - WINS + 1
#define WO 154
#define DOUT 90
#define CSTRIDE (H*W*DD)   // per-(b,c) channel stride

// Tile config
#define TH 8
#define TW 8
#define TD 16
#define IH 14            // TH + WINS - 1
#define IW 14
#define NCOL (IH * IW)   // 196
#define ID 24            // staged d extent per column (22 used, padded to 6 x float4)
#define IDU 22           // used d extent
#define NV 6             // float4s per column
#define HTILES 20
#define WTILES 20
#define DTILES 6
#define NBC 8            // B*C
#define DPB 23           // sB dd-stride (pad: 22 -> 23 f4, softens phase-C strided reads)

__device__ __forceinline__ float sval(float c0, float c1, float c2) {
    // c0=S_m, c1=S_tm, c2=S_t2m over the 343-voxel window; t = m?sigmoid:0.5
    const float S_t  = c1 + 0.5f  * (343.0f - c0);
    const float S_t2 = c2 + 0.25f * (343.0f - c0);
    const float inv  = 1.0f / 343.0f;
    const float ux   = S_t  * inv;
    const float uy   = c0   * inv;
    const float uxx  = S_t2 * inv;
    const float uxy  = c1   * inv;
    const float covn = 49.0f / 48.0f;   // WIN^2/(WIN^2-1)
    const float cc   = 0.00045f;        // (0.03*data_range)^2/2, data_range==1
    const float vx  = covn * (uxx - ux * ux);
    const float vy  = covn * (uy  - uy * uy);
    const float vxy = covn * (uxy - ux * uy);
    return (vxy + cc) / (vx * vy + cc);
}

__global__ __launch_bounds__(256)
void structure_loss_main(const float* __restrict__ x,
                         const int* __restrict__ y,
                         double* __restrict__ acc) {
    // sA: W-window sums, fields packed f4: [ih][wo][dd]  14*8*22*16 = 39,424 B
    __shared__ float4 sA[IH * TW * IDU];
    // vs (phase 0/A input) and sB (phase B/C) are never live together
    __shared__ union {
        float  vs[NCOL * ID];        // 18,816 B ; v = (y==cl ? +sig : -sig)
        float4 sB[TH * TW * DPB];    // 23,552 B ; H-window sums [ho][wo][dd(pad)]
    } u;

    const int dt = blockIdx.x;                 // 0..5
    const int wt = blockIdx.y;                 // 0..19
    const int z  = blockIdx.z;                 // 0..159
    const int bc = z / HTILES;
    const int ht = z - bc * HTILES;
    const int b  = bc >> 2;
    const int cl = bc & 3;

    const int h0 = ht * TH, w0 = wt * TW, d0 = dt * TD;

    const float* xc = x + ((size_t)b * 4 + cl) * (size_t)CSTRIDE;
    const int*   yc = y + (size_t)b * (size_t)CSTRIDE;

    const int t = threadIdx.x;

    // ---- Phase 0: coalesced vector staging. sign bit = one-hot mask ----
    for (int i = t; i < NCOL * NV; i += 256) {          // 1176 float4-items
        const int col = i / NV, q = i - col * NV;
        const int ih = col / IW, iw = col - ih * IW;
        const int h = min(h0 + ih, H - 1);
        const int w = min(w0 + iw, W - 1);
        const int dbase = d0 + 4 * q;
        float4 vv;
        if (dbase < DD) {
            const size_t off = ((size_t)h * W + w) * DD + dbase;
            const float4 xv = *(const float4*)(xc + off);
            const int4   yv = *(const int4*)(yc + off);
            const float s0 = 1.0f / (1.0f + __expf(-xv.x));
            const float s1 = 1.0f / (1.0f + __expf(-xv.y));
            const float s2 = 1.0f / (1.0f + __expf(-xv.z));
            const float s3 = 1.0f / (1.0f + __expf(-xv.w));
            vv.x = (yv.x == cl) ? s0 : -s0;
            vv.y = (yv.y == cl) ? s1 : -s1;
            vv.z = (yv.z == cl) ? s2 : -s2;
            vv.w = (yv.w == cl) ? s3 : -s3;
        } else {
            vv = make_float4(0.f, 0.f, 0.f, 0.f);   // feeds only discarded outputs
        }
        *(float4*)&u.vs[col * ID + 4 * q] = vv;
    }
    __syncthreads();

    // ---- Phase A: W-window, slide over iw in registers. Items (ih,dd) = 308 ----
    for (int j = t; j < IH * IDU; j += 256) {
        const int ih = j / IDU, dd = j - ih * IDU;
        float v[IW];
#pragma unroll
        for (int iw = 0; iw < IW; iw++) v[iw] = u.vs[(ih * IW + iw) * ID + dd];
        float s0 = 0.f, s1 = 0.f, s2 = 0.f;
#pragma unroll
        for (int iw = 0; iw < WINS; iw++) {
            const float p = fmaxf(v[iw], 0.f);
            s0 += (v[iw] > 0.f) ? 1.f : 0.f;
            s1 += p;
            s2 += p * v[iw];
        }
        sA[(ih * TW + 0) * IDU + dd] = make_float4(s0, s1, s2, 0.f);
#pragma unroll
        for (int wo = 1; wo < TW; wo++) {
            const float a = v[wo + 6], bb = v[wo - 1];
            const float pa_ = fmaxf(a, 0.f), pb_ = fmaxf(bb, 0.f);
            s0 += ((a > 0.f) ? 1.f : 0.f) - ((bb > 0.f) ? 1.f : 0.f);
            s1 += pa_ - pb_;
            s2 += pa_ * a - pb_ * bb;
            sA[(ih * TW + wo) * IDU + dd] = make_float4(s0, s1, s2, 0.f);
        }
    }
    __syncthreads();   // sA ready; vs reads retired before sB overwrites the union

    // ---- Phase B: H-window, slide over ih in registers. Items (wo,dd) = 176 ----
    if (t < TW * IDU) {
        const int wo = t / IDU, dd = t - wo * IDU;
        float4 f[IH];
#pragma unroll
        for (int ih = 0; ih < IH; ih++) f[ih] = sA[(ih * TW + wo) * IDU + dd];
        float s0 = 0.f, s1 = 0.f, s2 = 0.f;
#pragma unroll
        for (int ih = 0; ih < WINS; ih++) { s0 += f[ih].x; s1 += f[ih].y; s2 += f[ih].z; }
        u.sB[(0 * TW + wo) * DPB + dd] = make_float4(s0, s1, s2, 0.f);
#pragma unroll
        for (int ho = 1; ho < TH; ho++) {
            s0 += f[ho + 6].x - f[ho - 1].x;
            s1 += f[ho + 6].y - f[ho - 1].y;
            s2 += f[ho + 6].z - f[ho - 1].z;
            u.sB[(ho * TW + wo) * DPB + dd] = make_float4(s0, s1, s2, 0.f);
        }
    }
    __syncthreads();

    // ---- Phase C: D-window, slide over dd in a register ring. One wave (64 lanes) ----
    float lsum = 0.f;
    if (t < TH * TW) {
        const int ho = t >> 3, wo = t & 7;
        const int hg = h0 + ho, wg = w0 + wo;
        if (hg < HO && wg < WO) {
            const int base = (ho * TW + wo) * DPB;
            float4 ring[WINS];
            float s0 = 0.f, s1 = 0.f, s2 = 0.f;
#pragma unroll
            for (int k = 0; k < WINS; k++) {
                ring[k] = u.sB[base + k];
                s0 += ring[k].x; s1 += ring[k].y; s2 += ring[k].z;
            }
            lsum += sval(s0, s1, s2);                 // dg=0 always valid (d0<=80<90)
#pragma unroll
            for (int dg = 1; dg < TD; dg++) {
                const float4 nf = u.sB[base + dg + 6];
                const int r = (dg - 1) % WINS;        // static after unroll
                s0 += nf.x - ring[r].x;
                s1 += nf.y - ring[r].y;
                s2 += nf.z - ring[r].z;
                ring[r] = nf;
                if (d0 + dg < DOUT) lsum += sval(s0, s1, s2);
            }
        }
    }

    // All nonzero lsum lives in wave 0 -> single wave shuffle reduce, one atomic
    if (t < 64) {
#pragma unroll
        for (int off = 32; off > 0; off >>= 1) lsum += __shfl_down(lsum, off, 64);
        if (t == 0) atomicAdd(acc, (double)lsum);
    }
}

__global__ void structure_loss_finalize(const double* __restrict__ acc,
                                        float* __restrict__ out) {
    out[0] = 1.0f - (float)(acc[0] / 17075520.0);   // 8*154*154*90
}

extern "C" void kernel_launch(void* const* d_in, const int* in_sizes, int n_in,
                              void* d_out, int out_size, void* d_ws, size_t ws_size,
                              hipStream_t stream) {
    const float* x = (const float*)d_in[0];
    const int*   y = (const int*)d_in[1];
    double* acc = (double*)d_ws;

    hipMemsetAsync(d_ws, 0, sizeof(double), stream);

    dim3 grid(DTILES, WTILES, NBC * HTILES);   // (6, 20, 160) = 19200 blocks
    structure_loss_main<<<grid, 256, 0, stream>>>(x, y, acc);
    structure_loss_finalize<<<1, 1, 0, stream>>>(acc, (float*)d_out);
}